// Round 5
// baseline (569.257 us; speedup 1.0000x reference)
//
#include <hip/hip_runtime.h>
#include <cmath>

#define B_SZ 512
#define D_SZ 128
#define K_SZ 4096
#define NDATA 500000
#define ENTRIES (B_SZ * K_SZ)   // 2,097,152
#define TEMP 0.07f
#define MOM 0.5f
#define EPSN 1e-12f
#define NSCAN_BLKS ((NDATA + 1023) / 1024)  // 489

typedef float f32x4 __attribute__((ext_vector_type(4)));

// ---------------- normalize s,t + pos logits ----------------
__global__ void knorm(const float* __restrict__ s_in, const float* __restrict__ t_in,
                      float* __restrict__ s_n, float* __restrict__ t_n,
                      float* __restrict__ pos) {
    int b = blockIdx.x;
    int l = threadIdx.x;  // 64 lanes, 2 floats each
    float2 sv = ((const float2*)(s_in + b * D_SZ))[l];
    float2 tv = ((const float2*)(t_in + b * D_SZ))[l];
    float ss = sv.x * sv.x + sv.y * sv.y;
    float tt = tv.x * tv.x + tv.y * tv.y;
    for (int m = 1; m < 64; m <<= 1) {
        ss += __shfl_xor(ss, m, 64);
        tt += __shfl_xor(tt, m, 64);
    }
    float sinv = 1.0f / fmaxf(sqrtf(ss), EPSN);
    float tinv = 1.0f / fmaxf(sqrtf(tt), EPSN);
    float2 sn = {sv.x * sinv, sv.y * sinv};
    float2 tn = {tv.x * tinv, tv.y * tinv};
    ((float2*)(s_n + b * D_SZ))[l] = sn;
    ((float2*)(t_n + b * D_SZ))[l] = tn;
    float d = sn.x * tn.x + sn.y * tn.y;
    for (int m = 1; m < 64; m <<= 1) d += __shfl_xor(d, m, 64);
    if (l == 0) pos[b] = d * (1.0f / TEMP);
}

// ---------------- inverted index: histogram ----------------
__global__ void khist(const int* __restrict__ negidx, int* __restrict__ hist) {
    int t = blockIdx.x * 256 + threadIdx.x;  // 524288 threads, one int4 each
    int4 v = ((const int4*)negidx)[t];
    atomicAdd(&hist[v.x], 1);
    atomicAdd(&hist[v.y], 1);
    atomicAdd(&hist[v.z], 1);
    atomicAdd(&hist[v.w], 1);
}

// ---------------- scan pass 1: per-block exclusive scan ----------------
__global__ void kscan1(const int* __restrict__ hist, int* __restrict__ off,
                       int* __restrict__ bsum) {
    __shared__ int sc[256];
    int blk = blockIdx.x, t = threadIdx.x;
    int base = blk * 1024 + t * 4;
    int4 a = {0, 0, 0, 0};
    if (base < NDATA) a = ((const int4*)hist)[base >> 2];
    int s = a.x + a.y + a.z + a.w;
    sc[t] = s;
    __syncthreads();
    for (int d = 1; d < 256; d <<= 1) {
        int v = (t >= d) ? sc[t - d] : 0;
        __syncthreads();
        sc[t] += v;
        __syncthreads();
    }
    int excl = sc[t] - s;
    if (base < NDATA) {
        int4 o;
        o.x = excl;
        o.y = o.x + a.x;
        o.z = o.y + a.y;
        o.w = o.z + a.z;
        ((int4*)off)[base >> 2] = o;
    }
    if (t == 255) bsum[blk] = sc[255];
}

// ---------------- scan pass 2: scan block sums (1 block) ----------------
__global__ void kscan2(int* __restrict__ bsum) {
    __shared__ int sc[512];
    int t = threadIdx.x;
    int v = (t < NSCAN_BLKS) ? bsum[t] : 0;
    sc[t] = v;
    __syncthreads();
    for (int d = 1; d < 512; d <<= 1) {
        int u = (t >= d) ? sc[t - d] : 0;
        __syncthreads();
        sc[t] += u;
        __syncthreads();
    }
    if (t < NSCAN_BLKS) bsum[t] = sc[t] - v;  // exclusive
}

// ---------------- scan pass 3: add block offsets, init cursor ----------------
__global__ void kscan3(int* __restrict__ off, const int* __restrict__ bsum,
                       int* __restrict__ cursor) {
    int blk = blockIdx.x, t = threadIdx.x;
    int base = blk * 1024 + t * 4;
    if (base >= NDATA) return;
    int add = bsum[blk];
    int4 o = ((const int4*)off)[base >> 2];
    o.x += add; o.y += add; o.z += add; o.w += add;
    ((int4*)off)[base >> 2] = o;
    ((int4*)cursor)[base >> 2] = o;
}

// ---------------- scatter entries into row buckets ----------------
__global__ void kscatter(const int* __restrict__ negidx, int* __restrict__ cursor,
                         int* __restrict__ entry) {
    int t = blockIdx.x * 256 + threadIdx.x;  // one int4 each
    int4 v = ((const int4*)negidx)[t];
    int e = t * 4;  // e = b*4096 + k (negidx is [B][K] row-major)
    int p0 = atomicAdd(&cursor[v.x], 1); entry[p0] = e;
    int p1 = atomicAdd(&cursor[v.y], 1); entry[p1] = e + 1;
    int p2 = atomicAdd(&cursor[v.z], 1); entry[p2] = e + 2;
    int p3 = atomicAdd(&cursor[v.w], 1); entry[p3] = e + 3;
}

// ---------------- main pass: sequential bank sweep = copy + dots ----------------
__global__ __launch_bounds__(256) void kmain(const float* __restrict__ bank,
                                             float* __restrict__ out /* d_out */,
                                             const int* __restrict__ off,
                                             const int* __restrict__ hist,
                                             const int* __restrict__ entry,
                                             const float* __restrict__ s_n,
                                             float* __restrict__ logits) {
    const int tid = threadIdx.x;
    const int grp = tid >> 5;   // 8 groups of 32 lanes; one row per group
    const int lane = tid & 31;
    const long long r = blockIdx.x * 8LL + grp;  // row index, < 500000
    const long long j = r * 32 + lane;           // global float4 index
    const f32x4* bank4 = (const f32x4*)bank;
    f32x4 v = bank4[j];  // this group's row, 4 floats per lane

    // copy role: out[1 + i] = bank[i], aligned 16B stores
    f32x4* out4 = (f32x4*)out;
    if (j > 0) {
        float p = bank[4 * j - 1];  // neighbor element, L1/L2-hit
        f32x4 w;
        w.x = p; w.y = v.x; w.z = v.y; w.w = v.z;
        out4[j] = w;
    } else {
        out[1] = v.x; out[2] = v.y; out[3] = v.z;
        out[(long long)NDATA * D_SZ] = bank[(long long)NDATA * D_SZ - 1];
    }

    // dot products for every (b,k) entry referencing this row
    int start = off[r];
    int cnt = hist[r];
    const f32x4* sn4 = (const f32x4*)s_n;
    for (int i = 0; i < cnt; ++i) {
        int e = entry[start + i];
        int b = e >> 12;
        f32x4 sv = sn4[b * 32 + lane];  // L2-resident (256 KB)
        float d = v.x * sv.x + v.y * sv.y + v.z * sv.z + v.w * sv.w;
        d += __shfl_xor(d, 1, 32);
        d += __shfl_xor(d, 2, 32);
        d += __shfl_xor(d, 4, 32);
        d += __shfl_xor(d, 8, 32);
        d += __shfl_xor(d, 16, 32);
        if (lane == 0) logits[e] = d * (1.0f / TEMP);
    }
}

// ---------------- LSE over logits per batch row ----------------
__global__ void klse(const float* __restrict__ logits, float2* __restrict__ partials) {
    __shared__ float rm[256];
    __shared__ float rs[256];
    int b = blockIdx.x, t = threadIdx.x;
    const f32x4* lg4 = (const f32x4*)(logits + b * K_SZ);
    float M = -INFINITY, S = 0.0f;
    for (int k = t; k < K_SZ / 4; k += 256) {  // 4 iters, float4 each
        f32x4 L = lg4[k];
        float m0 = fmaxf(fmaxf(L.x, L.y), fmaxf(L.z, L.w));
        float mn = fmaxf(M, m0);
        S = S * __expf(M - mn) + __expf(L.x - mn) + __expf(L.y - mn) +
            __expf(L.z - mn) + __expf(L.w - mn);
        M = mn;
    }
    rm[t] = M;
    rs[t] = S;
    __syncthreads();
    for (int o = 128; o > 0; o >>= 1) {
        if (t < o) {
            float m2 = rm[t + o], s2 = rs[t + o];
            float mn = fmaxf(rm[t], m2);
            rs[t] = rs[t] * __expf(rm[t] - mn) + s2 * __expf(m2 - mn);
            rm[t] = mn;
        }
        __syncthreads();
    }
    if (t == 0) partials[b] = make_float2(rm[0], rs[0]);
}

// ---------------- momentum scatter-update (last-wins) ----------------
__global__ void kupdate(const int* __restrict__ indices, const float* __restrict__ bank,
                        const float* __restrict__ t_n, float* __restrict__ outBank /* d_out+1 */) {
    int j = blockIdx.x;
    int l = threadIdx.x;  // 64
    int idx = indices[j];
    for (int j2 = j + 1; j2 < B_SZ; ++j2)
        if (indices[j2] == idx) return;  // last occurrence wins
    float2 bv = ((const float2*)(bank + (long long)idx * D_SZ))[l];
    float2 tv = ((const float2*)(t_n + j * D_SZ))[l];
    float2 u = {MOM * bv.x + (1.0f - MOM) * tv.x, MOM * bv.y + (1.0f - MOM) * tv.y};
    float ss = u.x * u.x + u.y * u.y;
    for (int m = 1; m < 64; m <<= 1) ss += __shfl_xor(ss, m, 64);
    float inv = 1.0f / fmaxf(sqrtf(ss), EPSN);
    float* dst = outBank + (long long)idx * D_SZ + l * 2;
    dst[0] = u.x * inv;
    dst[1] = u.y * inv;
}

// ---------------- final loss ----------------
__global__ void kfinal(const float2* __restrict__ partials, const float* __restrict__ pos,
                       float* __restrict__ out) {
    __shared__ float red[B_SZ];
    int t = threadIdx.x;  // 512
    float2 ms = partials[t];
    float M = ms.x, S = ms.y;
    float pl = pos[t];
    float mn = fmaxf(M, pl);
    S = S * __expf(M - mn) + __expf(pl - mn);
    M = mn;
    red[t] = M + logf(S) - pl;
    __syncthreads();
    for (int o = 256; o > 0; o >>= 1) {
        if (t < o) red[t] += red[t + o];
        __syncthreads();
    }
    if (t == 0) out[0] = red[0] * (1.0f / (float)B_SZ);
}

extern "C" void kernel_launch(void* const* d_in, const int* in_sizes, int n_in,
                              void* d_out, int out_size, void* d_ws, size_t ws_size,
                              hipStream_t stream) {
    const float* student = (const float*)d_in[0];
    const float* teacher = (const float*)d_in[1];
    const float* bank    = (const float*)d_in[2];
    const int*   indices = (const int*)d_in[3];
    const int*   negidx  = (const int*)d_in[4];
    float* out = (float*)d_out;

    // workspace layout (~23.3 MB)
    float* s_n      = (float*)d_ws;                  // 65536 f
    float* t_n      = s_n + B_SZ * D_SZ;             // 65536 f
    float* pos      = t_n + B_SZ * D_SZ;             // 512 f
    float2* partials = (float2*)(pos + B_SZ);        // 512 float2
    int* hist   = (int*)(partials + B_SZ);           // 500000 i
    int* off    = hist + NDATA;                      // 500000 i
    int* cursor = off + NDATA;                       // 500000 i
    int* bsum   = cursor + NDATA;                    // 512 i
    int* entry  = bsum + 512;                        // 2,097,152 i
    float* logits = (float*)(entry + ENTRIES);       // 2,097,152 f

    hipMemsetAsync(hist, 0, NDATA * sizeof(int), stream);
    knorm<<<B_SZ, 64, 0, stream>>>(student, teacher, s_n, t_n, pos);
    khist<<<ENTRIES / 4 / 256, 256, 0, stream>>>(negidx, hist);
    kscan1<<<NSCAN_BLKS, 256, 0, stream>>>(hist, off, bsum);
    kscan2<<<1, 512, 0, stream>>>(bsum);
    kscan3<<<NSCAN_BLKS, 256, 0, stream>>>(off, bsum, cursor);
    kscatter<<<ENTRIES / 4 / 256, 256, 0, stream>>>(negidx, cursor, entry);
    kmain<<<NDATA / 8, 256, 0, stream>>>(bank, out, off, hist, entry, s_n, logits);
    klse<<<B_SZ, 256, 0, stream>>>(logits, partials);
    kupdate<<<B_SZ, 64, 0, stream>>>(indices, bank, t_n, out + 1);
    kfinal<<<1, B_SZ, 0, stream>>>(partials, pos, out);
}

// Round 6
// 281.219 us; speedup vs baseline: 2.0242x; 2.0242x over previous
//
#include <hip/hip_runtime.h>
#include <cmath>

#define B_SZ 512
#define D_SZ 128
#define K_SZ 4096
#define NDATA 500000
#define TEMP 0.07f
#define MOM 0.5f
#define EPSN 1e-12f
#define SPLIT 4

typedef float f32x4 __attribute__((ext_vector_type(4)));

// ---------------- kernel A: normalize s,t + pos logits ----------------
__global__ void knorm(const float* __restrict__ s_in, const float* __restrict__ t_in,
                      float* __restrict__ s_n, float* __restrict__ t_n,
                      float* __restrict__ pos) {
    int b = blockIdx.x;
    int l = threadIdx.x;  // 64 lanes, each handles 2 floats
    float2 sv = ((const float2*)(s_in + b * D_SZ))[l];
    float2 tv = ((const float2*)(t_in + b * D_SZ))[l];
    float ss = sv.x * sv.x + sv.y * sv.y;
    float tt = tv.x * tv.x + tv.y * tv.y;
    for (int m = 1; m < 64; m <<= 1) {
        ss += __shfl_xor(ss, m, 64);
        tt += __shfl_xor(tt, m, 64);
    }
    float sinv = 1.0f / fmaxf(sqrtf(ss), EPSN);
    float tinv = 1.0f / fmaxf(sqrtf(tt), EPSN);
    float2 sn = {sv.x * sinv, sv.y * sinv};
    float2 tn = {tv.x * tinv, tv.y * tinv};
    ((float2*)(s_n + b * D_SZ))[l] = sn;
    ((float2*)(t_n + b * D_SZ))[l] = tn;
    float d = sn.x * tn.x + sn.y * tn.y;
    for (int m = 1; m < 64; m <<= 1) d += __shfl_xor(d, m, 64);
    if (l == 0) pos[b] = d * (1.0f / TEMP);
}

// ---------------- kernel B: copy bank -> out+1 via wave-shuffle realign ----------------
// out4[j] = { src[4j-1], src[4j], src[4j+1], src[4j+2] }  for j in [1, 16M)
__global__ __launch_bounds__(256) void kcopy(const float* __restrict__ src,
                                             float* __restrict__ out /* d_out */) {
    const long long total = (long long)NDATA * D_SZ;  // 64,000,000
    const long long NV = total / 4;                   // 16,000,000
    long long t = blockIdx.x * 256LL + threadIdx.x;
    const long long nthr = gridDim.x * 256LL;
    const int lane = threadIdx.x & 63;
    if (t == 0) {
        out[1] = src[0]; out[2] = src[1]; out[3] = src[2];
        out[total] = src[total - 1];
    }
    const f32x4* src4 = (const f32x4*)src;
    f32x4* out4 = (f32x4*)out;
    for (long long j = 1 + t; j < NV; j += nthr) {
        f32x4 v = src4[j];                   // aligned 16B load
        float pw = __shfl_up(v.w, 1, 64);    // previous lane's last element
        if (lane == 0) pw = src[4 * j - 1];  // 1 scalar load per wave
        f32x4 w;
        w.x = pw; w.y = v.x; w.z = v.y; w.w = v.z;
        out4[j] = w;                         // aligned 16B store
    }
}

// ---------------- kernel C: momentum scatter-update (last-wins) ----------------
__global__ void kupdate(const int* __restrict__ indices, const float* __restrict__ bank,
                        const float* __restrict__ t_n, float* __restrict__ outBank /* d_out+1 */) {
    int j = blockIdx.x;
    int l = threadIdx.x;  // 64
    int idx = indices[j];
    // numpy fancy-assignment semantics: last occurrence wins
    for (int j2 = j + 1; j2 < B_SZ; ++j2)
        if (indices[j2] == idx) return;
    float2 bv = ((const float2*)(bank + (long long)idx * D_SZ))[l];
    float2 tv = ((const float2*)(t_n + j * D_SZ))[l];
    float2 u = {MOM * bv.x + (1.0f - MOM) * tv.x, MOM * bv.y + (1.0f - MOM) * tv.y};
    float ss = u.x * u.x + u.y * u.y;
    for (int m = 1; m < 64; m <<= 1) ss += __shfl_xor(ss, m, 64);
    float inv = 1.0f / fmaxf(sqrtf(ss), EPSN);
    float* dst = outBank + (long long)idx * D_SZ + l * 2;  // 4B-aligned only
    dst[0] = u.x * inv;
    dst[1] = u.y * inv;
}

// ---------------- kernel D: gather negatives, dot, online LSE partials (x4 unroll) ----------------
__global__ __launch_bounds__(256) void kneg(const float* __restrict__ bank,
                                            const int* __restrict__ negidx,
                                            const float* __restrict__ s_n,
                                            float2* __restrict__ partials) {
    const int split = blockIdx.x;
    const int b = blockIdx.y;
    __shared__ float s_lds[D_SZ];
    int tid = threadIdx.x;
    if (tid < 32) ((float4*)s_lds)[tid] = ((const float4*)(s_n + b * D_SZ))[tid];
    __syncthreads();
    const int lane = tid & 31;
    const int grp = tid >> 5;  // 8 groups of 32 lanes
    float4 sv = ((const float4*)s_lds)[lane];
    float m = -INFINITY, ssum = 0.0f;
    const int base = b * K_SZ + split * (K_SZ / SPLIT);
    const int iters = (K_SZ / SPLIT) / 32;  // 32; each group does 4 rows/iter
    for (int it = 0; it < iters; ++it) {
        int k = it * 32 + grp * 4;
        int4 idx = ((const int4*)(negidx + base + k))[0];
        float4 v0 = ((const float4*)(bank + (long long)idx.x * D_SZ))[lane];
        float4 v1 = ((const float4*)(bank + (long long)idx.y * D_SZ))[lane];
        float4 v2 = ((const float4*)(bank + (long long)idx.z * D_SZ))[lane];
        float4 v3 = ((const float4*)(bank + (long long)idx.w * D_SZ))[lane];
        float d0 = v0.x * sv.x + v0.y * sv.y + v0.z * sv.z + v0.w * sv.w;
        float d1 = v1.x * sv.x + v1.y * sv.y + v1.z * sv.z + v1.w * sv.w;
        float d2 = v2.x * sv.x + v2.y * sv.y + v2.z * sv.z + v2.w * sv.w;
        float d3 = v3.x * sv.x + v3.y * sv.y + v3.z * sv.z + v3.w * sv.w;
        for (int s = 1; s < 32; s <<= 1) {
            d0 += __shfl_xor(d0, s, 32);
            d1 += __shfl_xor(d1, s, 32);
            d2 += __shfl_xor(d2, s, 32);
            d3 += __shfl_xor(d3, s, 32);
        }
        d0 *= (1.0f / TEMP);
        d1 *= (1.0f / TEMP);
        d2 *= (1.0f / TEMP);
        d3 *= (1.0f / TEMP);
        float mx = fmaxf(fmaxf(d0, d1), fmaxf(d2, d3));
        float mn = fmaxf(m, mx);
        ssum = ssum * __expf(m - mn) + __expf(d0 - mn) + __expf(d1 - mn) +
               __expf(d2 - mn) + __expf(d3 - mn);
        m = mn;
    }
    __shared__ float2 gp[8];
    if (lane == 0) gp[grp] = make_float2(m, ssum);
    __syncthreads();
    if (tid == 0) {
        float M = gp[0].x, S = gp[0].y;
        for (int g = 1; g < 8; ++g) {
            float mg = gp[g].x, sg = gp[g].y;
            float mn = fmaxf(M, mg);
            S = S * __expf(M - mn) + sg * __expf(mg - mn);
            M = mn;
        }
        partials[b * SPLIT + split] = make_float2(M, S);
    }
}

// ---------------- kernel E: combine partials -> loss ----------------
__global__ void kfinal(const float2* __restrict__ partials, const float* __restrict__ pos,
                       float* __restrict__ out) {
    __shared__ float red[B_SZ];
    int t = threadIdx.x;  // 512 threads, one per batch row
    float M = -INFINITY, S = 0.0f;
    for (int p = 0; p < SPLIT; ++p) {
        float2 ms = partials[t * SPLIT + p];
        float mn = fmaxf(M, ms.x);
        S = S * __expf(M - mn) + ms.y * __expf(ms.x - mn);
        M = mn;
    }
    float pl = pos[t];
    float mn = fmaxf(M, pl);
    S = S * __expf(M - mn) + __expf(pl - mn);
    M = mn;
    float lse = M + logf(S);
    red[t] = lse - pl;
    __syncthreads();
    for (int off = 256; off > 0; off >>= 1) {
        if (t < off) red[t] += red[t + off];
        __syncthreads();
    }
    if (t == 0) out[0] = red[0] * (1.0f / (float)B_SZ);
}

extern "C" void kernel_launch(void* const* d_in, const int* in_sizes, int n_in,
                              void* d_out, int out_size, void* d_ws, size_t ws_size,
                              hipStream_t stream) {
    const float* student = (const float*)d_in[0];
    const float* teacher = (const float*)d_in[1];
    const float* bank    = (const float*)d_in[2];
    const int*   indices = (const int*)d_in[3];
    const int*   negidx  = (const int*)d_in[4];
    float* out = (float*)d_out;

    // workspace layout (floats)
    float* ws = (float*)d_ws;
    float* s_n      = ws;                       // 512*128
    float* t_n      = s_n + B_SZ * D_SZ;        // 512*128
    float* pos      = t_n + B_SZ * D_SZ;        // 512
    float2* partials = (float2*)(pos + B_SZ);   // 512*SPLIT float2

    // 1) normalize + pos logits (tiny)
    knorm<<<B_SZ, 64, 0, stream>>>(student, teacher, s_n, t_n, pos);
    // 2) gather first: warms L3 with the bank for the copy
    dim3 g(SPLIT, B_SZ);
    kneg<<<g, 256, 0, stream>>>(bank, negidx, s_n, partials);
    // 3) copy bank into output (offset 1), L3-warm reads
    kcopy<<<4096, 256, 0, stream>>>(bank, out);
    // 4) momentum scatter-update of indexed rows (after copy)
    kupdate<<<B_SZ, 64, 0, stream>>>(indices, bank, t_n, out + 1);
    // 5) final loss (also overwrites kcopy's junk at out[0])
    kfinal<<<1, B_SZ, 0, stream>>>(partials, pos, out);
}

// Round 7
// 272.211 us; speedup vs baseline: 2.0912x; 1.0331x over previous
//
#include <hip/hip_runtime.h>
#include <cmath>

#define B_SZ 512
#define D_SZ 128
#define K_SZ 4096
#define NDATA 500000
#define TEMP 0.07f
#define MOM 0.5f
#define EPSN 1e-12f
#define SPLIT 4

typedef float f32x4 __attribute__((ext_vector_type(4)));

// ---------------- kernel A: normalize s,t + pos logits ----------------
__global__ void knorm(const float* __restrict__ s_in, const float* __restrict__ t_in,
                      float* __restrict__ s_n, float* __restrict__ t_n,
                      float* __restrict__ pos) {
    int b = blockIdx.x;
    int l = threadIdx.x;  // 64 lanes, each handles 2 floats
    float2 sv = ((const float2*)(s_in + b * D_SZ))[l];
    float2 tv = ((const float2*)(t_in + b * D_SZ))[l];
    float ss = sv.x * sv.x + sv.y * sv.y;
    float tt = tv.x * tv.x + tv.y * tv.y;
    for (int m = 1; m < 64; m <<= 1) {
        ss += __shfl_xor(ss, m, 64);
        tt += __shfl_xor(tt, m, 64);
    }
    float sinv = 1.0f / fmaxf(sqrtf(ss), EPSN);
    float tinv = 1.0f / fmaxf(sqrtf(tt), EPSN);
    float2 sn = {sv.x * sinv, sv.y * sinv};
    float2 tn = {tv.x * tinv, tv.y * tinv};
    ((float2*)(s_n + b * D_SZ))[l] = sn;
    ((float2*)(t_n + b * D_SZ))[l] = tn;
    float d = sn.x * tn.x + sn.y * tn.y;
    for (int m = 1; m < 64; m <<= 1) d += __shfl_xor(d, m, 64);
    if (l == 0) pos[b] = d * (1.0f / TEMP);
}

// ---------------- copy halves: A = NT stores, B = regular stores ----------------
// out4[j] = { src[4j-1], src[4j], src[4j+1], src[4j+2] }
__global__ __launch_bounds__(256) void kcopyA(const float* __restrict__ src,
                                              float* __restrict__ out /* d_out */) {
    const long long total = (long long)NDATA * D_SZ;  // 64,000,000
    const long long NV = total / 4;                   // 16,000,000
    const long long HALF = NV / 2;
    long long t = blockIdx.x * 256LL + threadIdx.x;
    const long long nthr = gridDim.x * 256LL;
    const int lane = threadIdx.x & 63;
    if (t == 0) {
        out[1] = src[0]; out[2] = src[1]; out[3] = src[2];
        out[total] = src[total - 1];
    }
    const f32x4* src4 = (const f32x4*)src;
    f32x4* out4 = (f32x4*)out;
    for (long long j = 1 + t; j < HALF; j += nthr) {
        f32x4 v = src4[j];
        float pw = __shfl_up(v.w, 1, 64);
        if (lane == 0) pw = src[4 * j - 1];
        f32x4 w;
        w.x = pw; w.y = v.x; w.z = v.y; w.w = v.z;
        __builtin_nontemporal_store(w, out4 + j);
    }
}

__global__ __launch_bounds__(256) void kcopyB(const float* __restrict__ src,
                                              float* __restrict__ out /* d_out */) {
    const long long total = (long long)NDATA * D_SZ;
    const long long NV = total / 4;
    const long long HALF = NV / 2;
    long long t = blockIdx.x * 256LL + threadIdx.x;
    const long long nthr = gridDim.x * 256LL;
    const int lane = threadIdx.x & 63;
    const f32x4* src4 = (const f32x4*)src;
    f32x4* out4 = (f32x4*)out;
    for (long long j = HALF + t; j < NV; j += nthr) {
        f32x4 v = src4[j];
        float pw = __shfl_up(v.w, 1, 64);
        if (lane == 0) pw = src[4 * j - 1];
        f32x4 w;
        w.x = pw; w.y = v.x; w.z = v.y; w.w = v.z;
        out4[j] = w;
    }
}

// ---------------- kernel C: momentum scatter-update (last-wins) ----------------
__global__ void kupdate(const int* __restrict__ indices, const float* __restrict__ bank,
                        const float* __restrict__ t_n, float* __restrict__ outBank /* d_out+1 */) {
    int j = blockIdx.x;
    int l = threadIdx.x;  // 64
    int idx = indices[j];
    for (int j2 = j + 1; j2 < B_SZ; ++j2)
        if (indices[j2] == idx) return;  // last occurrence wins
    float2 bv = ((const float2*)(bank + (long long)idx * D_SZ))[l];
    float2 tv = ((const float2*)(t_n + j * D_SZ))[l];
    float2 u = {MOM * bv.x + (1.0f - MOM) * tv.x, MOM * bv.y + (1.0f - MOM) * tv.y};
    float ss = u.x * u.x + u.y * u.y;
    for (int m = 1; m < 64; m <<= 1) ss += __shfl_xor(ss, m, 64);
    float inv = 1.0f / fmaxf(sqrtf(ss), EPSN);
    float* dst = outBank + (long long)idx * D_SZ + l * 2;
    dst[0] = u.x * inv;
    dst[1] = u.y * inv;
}

// ---------------- kernel D: gather negatives, dot, online LSE partials (x4 unroll) ----------------
__global__ __launch_bounds__(256) void kneg(const float* __restrict__ bank,
                                            const int* __restrict__ negidx,
                                            const float* __restrict__ s_n,
                                            float2* __restrict__ partials) {
    const int split = blockIdx.x;
    const int b = blockIdx.y;
    __shared__ float s_lds[D_SZ];
    int tid = threadIdx.x;
    if (tid < 32) ((float4*)s_lds)[tid] = ((const float4*)(s_n + b * D_SZ))[tid];
    __syncthreads();
    const int lane = tid & 31;
    const int grp = tid >> 5;  // 8 groups of 32 lanes
    float4 sv = ((const float4*)s_lds)[lane];
    float m = -INFINITY, ssum = 0.0f;
    const int base = b * K_SZ + split * (K_SZ / SPLIT);
    const int iters = (K_SZ / SPLIT) / 32;  // 32; each group does 4 rows/iter
    for (int it = 0; it < iters; ++it) {
        int k = it * 32 + grp * 4;
        int4 idx = ((const int4*)(negidx + base + k))[0];
        float4 v0 = ((const float4*)(bank + (long long)idx.x * D_SZ))[lane];
        float4 v1 = ((const float4*)(bank + (long long)idx.y * D_SZ))[lane];
        float4 v2 = ((const float4*)(bank + (long long)idx.z * D_SZ))[lane];
        float4 v3 = ((const float4*)(bank + (long long)idx.w * D_SZ))[lane];
        float d0 = v0.x * sv.x + v0.y * sv.y + v0.z * sv.z + v0.w * sv.w;
        float d1 = v1.x * sv.x + v1.y * sv.y + v1.z * sv.z + v1.w * sv.w;
        float d2 = v2.x * sv.x + v2.y * sv.y + v2.z * sv.z + v2.w * sv.w;
        float d3 = v3.x * sv.x + v3.y * sv.y + v3.z * sv.z + v3.w * sv.w;
        for (int s = 1; s < 32; s <<= 1) {
            d0 += __shfl_xor(d0, s, 32);
            d1 += __shfl_xor(d1, s, 32);
            d2 += __shfl_xor(d2, s, 32);
            d3 += __shfl_xor(d3, s, 32);
        }
        d0 *= (1.0f / TEMP);
        d1 *= (1.0f / TEMP);
        d2 *= (1.0f / TEMP);
        d3 *= (1.0f / TEMP);
        float mx = fmaxf(fmaxf(d0, d1), fmaxf(d2, d3));
        float mn = fmaxf(m, mx);
        ssum = ssum * __expf(m - mn) + __expf(d0 - mn) + __expf(d1 - mn) +
               __expf(d2 - mn) + __expf(d3 - mn);
        m = mn;
    }
    __shared__ float2 gp[8];
    if (lane == 0) gp[grp] = make_float2(m, ssum);
    __syncthreads();
    if (tid == 0) {
        float M = gp[0].x, S = gp[0].y;
        for (int g = 1; g < 8; ++g) {
            float mg = gp[g].x, sg = gp[g].y;
            float mn = fmaxf(M, mg);
            S = S * __expf(M - mn) + sg * __expf(mg - mn);
            M = mn;
        }
        partials[b * SPLIT + split] = make_float2(M, S);
    }
}

// ---------------- kernel E: combine partials -> loss ----------------
__global__ void kfinal(const float2* __restrict__ partials, const float* __restrict__ pos,
                       float* __restrict__ out) {
    __shared__ float red[B_SZ];
    int t = threadIdx.x;  // 512 threads, one per batch row
    float M = -INFINITY, S = 0.0f;
    for (int p = 0; p < SPLIT; ++p) {
        float2 ms = partials[t * SPLIT + p];
        float mn = fmaxf(M, ms.x);
        S = S * __expf(M - mn) + ms.y * __expf(ms.x - mn);
        M = mn;
    }
    float pl = pos[t];
    float mn = fmaxf(M, pl);
    S = S * __expf(M - mn) + __expf(pl - mn);
    M = mn;
    float lse = M + logf(S);
    red[t] = lse - pl;
    __syncthreads();
    for (int off = 256; off > 0; off >>= 1) {
        if (t < off) red[t] += red[t + off];
        __syncthreads();
    }
    if (t == 0) out[0] = red[0] * (1.0f / (float)B_SZ);
}

extern "C" void kernel_launch(void* const* d_in, const int* in_sizes, int n_in,
                              void* d_out, int out_size, void* d_ws, size_t ws_size,
                              hipStream_t stream) {
    const float* student = (const float*)d_in[0];
    const float* teacher = (const float*)d_in[1];
    const float* bank    = (const float*)d_in[2];
    const int*   indices = (const int*)d_in[3];
    const int*   negidx  = (const int*)d_in[4];
    float* out = (float*)d_out;

    // workspace layout (floats)
    float* ws = (float*)d_ws;
    float* s_n      = ws;                       // 512*128
    float* t_n      = s_n + B_SZ * D_SZ;        // 512*128
    float* pos      = t_n + B_SZ * D_SZ;        // 512
    float2* partials = (float2*)(pos + B_SZ);   // 512*SPLIT float2

    // 1) normalize + pos logits (tiny)
    knorm<<<B_SZ, 64, 0, stream>>>(student, teacher, s_n, t_n, pos);
    // 2) copy bank into output (offset 1): A/B halves — NT vs regular stores.
    //    Copy first: sequential bank read warms L3 for the gather.
    kcopyA<<<2048, 256, 0, stream>>>(bank, out);
    kcopyB<<<2048, 256, 0, stream>>>(bank, out);
    // 3) momentum scatter-update of indexed rows (after copy)
    kupdate<<<B_SZ, 64, 0, stream>>>(indices, bank, t_n, out + 1);
    // 4) gather + online LSE on L3-warm bank
    dim3 g(SPLIT, B_SZ);
    kneg<<<g, 256, 0, stream>>>(bank, negidx, s_n, partials);
    // 5) final loss
    kfinal<<<1, B_SZ, 0, stream>>>(partials, pos, out);
}

// Round 8
// 218.720 us; speedup vs baseline: 2.6027x; 1.2446x over previous
//
#include <hip/hip_runtime.h>
#include <cmath>

#define B_SZ 512
#define D_SZ 128
#define K_SZ 4096
#define NDATA 500000
#define TEMP 0.07f
#define MOM 0.5f
#define EPSN 1e-12f
#define SPLIT 8
#define WSB_OFF (1 << 20)  // bf16 shadow bank offset in d_ws (bytes)

typedef float f32x4 __attribute__((ext_vector_type(4)));
typedef unsigned short u16x4 __attribute__((ext_vector_type(4)));

__device__ inline unsigned short f2bf(float x) {  // f32 -> bf16 RNE
    unsigned int u = __float_as_uint(x);
    return (unsigned short)((u + 0x7FFF + ((u >> 16) & 1)) >> 16);
}
__device__ inline float bf2f(unsigned short h) {  // bf16 -> f32 exact
    return __uint_as_float(((unsigned int)h) << 16);
}

// ---------------- kernel A: normalize s,t + pos logits ----------------
__global__ void knorm(const float* __restrict__ s_in, const float* __restrict__ t_in,
                      float* __restrict__ s_n, float* __restrict__ t_n,
                      float* __restrict__ pos) {
    int b = blockIdx.x;
    int l = threadIdx.x;  // 64 lanes, 2 floats each
    float2 sv = ((const float2*)(s_in + b * D_SZ))[l];
    float2 tv = ((const float2*)(t_in + b * D_SZ))[l];
    float ss = sv.x * sv.x + sv.y * sv.y;
    float tt = tv.x * tv.x + tv.y * tv.y;
    for (int m = 1; m < 64; m <<= 1) {
        ss += __shfl_xor(ss, m, 64);
        tt += __shfl_xor(tt, m, 64);
    }
    float sinv = 1.0f / fmaxf(sqrtf(ss), EPSN);
    float tinv = 1.0f / fmaxf(sqrtf(tt), EPSN);
    float2 sn = {sv.x * sinv, sv.y * sinv};
    float2 tn = {tv.x * tinv, tv.y * tinv};
    ((float2*)(s_n + b * D_SZ))[l] = sn;
    ((float2*)(t_n + b * D_SZ))[l] = tn;
    float d = sn.x * tn.x + sn.y * tn.y;
    for (int m = 1; m < 64; m <<= 1) d += __shfl_xor(d, m, 64);
    if (l == 0) pos[b] = d * (1.0f / TEMP);
}

// ---------------- copy: bank -> out+1 (NT f32 streams) + bf16 shadow (cached) ----------------
__global__ __launch_bounds__(256) void kcopy_emit(const float* __restrict__ src,
                                                  float* __restrict__ out /* d_out */,
                                                  u16x4* __restrict__ wsb) {
    const long long total = (long long)NDATA * D_SZ;  // 64,000,000
    const long long NV = total / 4;                   // 16,000,000
    long long t = blockIdx.x * 256LL + threadIdx.x;
    const long long nthr = gridDim.x * 256LL;
    const int lane = threadIdx.x & 63;
    const f32x4* src4 = (const f32x4*)src;
    f32x4* out4 = (f32x4*)out;
    for (long long j = t; j < NV; j += nthr) {
        f32x4 v = __builtin_nontemporal_load(src4 + j);
        u16x4 h;
        h.x = f2bf(v.x); h.y = f2bf(v.y); h.z = f2bf(v.z); h.w = f2bf(v.w);
        wsb[j] = h;  // regular store -> stays in L3 for the gather
        float pw = __shfl_up(v.w, 1, 64);
        if (lane == 0 && j > 0) pw = src[4 * j - 1];
        if (j > 0) {
            f32x4 w;
            w.x = pw; w.y = v.x; w.z = v.y; w.w = v.z;
            __builtin_nontemporal_store(w, out4 + j);
        } else {
            out[1] = v.x; out[2] = v.y; out[3] = v.z;
            out[total] = src[total - 1];
        }
    }
}

// fallback copy (no shadow emit)
__global__ __launch_bounds__(256) void kcopy_plain(const float* __restrict__ src,
                                                   float* __restrict__ out /* d_out */) {
    const long long total = (long long)NDATA * D_SZ;
    const long long NV = total / 4;
    long long t = blockIdx.x * 256LL + threadIdx.x;
    const long long nthr = gridDim.x * 256LL;
    const int lane = threadIdx.x & 63;
    const f32x4* src4 = (const f32x4*)src;
    f32x4* out4 = (f32x4*)out;
    for (long long j = t; j < NV; j += nthr) {
        f32x4 v = src4[j];
        float pw = __shfl_up(v.w, 1, 64);
        if (lane == 0 && j > 0) pw = src[4 * j - 1];
        if (j > 0) {
            f32x4 w;
            w.x = pw; w.y = v.x; w.z = v.y; w.w = v.z;
            out4[j] = w;
        } else {
            out[1] = v.x; out[2] = v.y; out[3] = v.z;
            out[total] = src[total - 1];
        }
    }
}

// ---------------- gather from bf16 shadow bank ----------------
__global__ __launch_bounds__(256) void kneg_bf16(const u16x4* __restrict__ wsb,
                                                 const int* __restrict__ negidx,
                                                 const float* __restrict__ s_n,
                                                 float2* __restrict__ partials) {
    const int split = blockIdx.x;  // 0..SPLIT-1
    const int b = blockIdx.y;
    __shared__ float s_lds[D_SZ];
    int tid = threadIdx.x;
    if (tid < 32) ((float4*)s_lds)[tid] = ((const float4*)(s_n + b * D_SZ))[tid];
    __syncthreads();
    const int lane = tid & 31;
    const int grp = tid >> 5;  // 8 groups
    float4 sv = ((const float4*)s_lds)[lane];
    float m = -INFINITY, ssum = 0.0f;
    const int KB = K_SZ / SPLIT;            // 512
    const int base = b * K_SZ + split * KB;
    const int iters = KB / 32;              // 16; 8 groups x 4 rows/iter
    for (int it = 0; it < iters; ++it) {
        int k = it * 32 + grp * 4;
        int4 idx = *(const int4*)(negidx + base + k);
        u16x4 h0 = wsb[(long long)idx.x * 32 + lane];
        u16x4 h1 = wsb[(long long)idx.y * 32 + lane];
        u16x4 h2 = wsb[(long long)idx.z * 32 + lane];
        u16x4 h3 = wsb[(long long)idx.w * 32 + lane];
        float d0 = bf2f(h0.x) * sv.x + bf2f(h0.y) * sv.y + bf2f(h0.z) * sv.z + bf2f(h0.w) * sv.w;
        float d1 = bf2f(h1.x) * sv.x + bf2f(h1.y) * sv.y + bf2f(h1.z) * sv.z + bf2f(h1.w) * sv.w;
        float d2 = bf2f(h2.x) * sv.x + bf2f(h2.y) * sv.y + bf2f(h2.z) * sv.z + bf2f(h2.w) * sv.w;
        float d3 = bf2f(h3.x) * sv.x + bf2f(h3.y) * sv.y + bf2f(h3.z) * sv.z + bf2f(h3.w) * sv.w;
        for (int s = 1; s < 32; s <<= 1) {
            d0 += __shfl_xor(d0, s, 32);
            d1 += __shfl_xor(d1, s, 32);
            d2 += __shfl_xor(d2, s, 32);
            d3 += __shfl_xor(d3, s, 32);
        }
        d0 *= (1.0f / TEMP);
        d1 *= (1.0f / TEMP);
        d2 *= (1.0f / TEMP);
        d3 *= (1.0f / TEMP);
        float mx = fmaxf(fmaxf(d0, d1), fmaxf(d2, d3));
        float mn = fmaxf(m, mx);
        ssum = ssum * __expf(m - mn) + __expf(d0 - mn) + __expf(d1 - mn) +
               __expf(d2 - mn) + __expf(d3 - mn);
        m = mn;
    }
    __shared__ float2 gp[8];
    if (lane == 0) gp[grp] = make_float2(m, ssum);
    __syncthreads();
    if (tid == 0) {
        float M = gp[0].x, S = gp[0].y;
        for (int g = 1; g < 8; ++g) {
            float mg = gp[g].x, sg = gp[g].y;
            float mn = fmaxf(M, mg);
            S = S * __expf(M - mn) + sg * __expf(mg - mn);
            M = mn;
        }
        partials[b * SPLIT + split] = make_float2(M, S);
    }
}

// fallback: f32 gather straight from bank
__global__ __launch_bounds__(256) void kneg_f32(const float* __restrict__ bank,
                                                const int* __restrict__ negidx,
                                                const float* __restrict__ s_n,
                                                float2* __restrict__ partials) {
    const int split = blockIdx.x;
    const int b = blockIdx.y;
    __shared__ float s_lds[D_SZ];
    int tid = threadIdx.x;
    if (tid < 32) ((float4*)s_lds)[tid] = ((const float4*)(s_n + b * D_SZ))[tid];
    __syncthreads();
    const int lane = tid & 31;
    const int grp = tid >> 5;
    float4 sv = ((const float4*)s_lds)[lane];
    float m = -INFINITY, ssum = 0.0f;
    const int KB = K_SZ / SPLIT;
    const int base = b * K_SZ + split * KB;
    const int iters = KB / 32;
    for (int it = 0; it < iters; ++it) {
        int k = it * 32 + grp * 4;
        int4 idx = *(const int4*)(negidx + base + k);
        float4 v0 = ((const float4*)(bank + (long long)idx.x * D_SZ))[lane];
        float4 v1 = ((const float4*)(bank + (long long)idx.y * D_SZ))[lane];
        float4 v2 = ((const float4*)(bank + (long long)idx.z * D_SZ))[lane];
        float4 v3 = ((const float4*)(bank + (long long)idx.w * D_SZ))[lane];
        float d0 = v0.x * sv.x + v0.y * sv.y + v0.z * sv.z + v0.w * sv.w;
        float d1 = v1.x * sv.x + v1.y * sv.y + v1.z * sv.z + v1.w * sv.w;
        float d2 = v2.x * sv.x + v2.y * sv.y + v2.z * sv.z + v2.w * sv.w;
        float d3 = v3.x * sv.x + v3.y * sv.y + v3.z * sv.z + v3.w * sv.w;
        for (int s = 1; s < 32; s <<= 1) {
            d0 += __shfl_xor(d0, s, 32);
            d1 += __shfl_xor(d1, s, 32);
            d2 += __shfl_xor(d2, s, 32);
            d3 += __shfl_xor(d3, s, 32);
        }
        d0 *= (1.0f / TEMP);
        d1 *= (1.0f / TEMP);
        d2 *= (1.0f / TEMP);
        d3 *= (1.0f / TEMP);
        float mx = fmaxf(fmaxf(d0, d1), fmaxf(d2, d3));
        float mn = fmaxf(m, mx);
        ssum = ssum * __expf(m - mn) + __expf(d0 - mn) + __expf(d1 - mn) +
               __expf(d2 - mn) + __expf(d3 - mn);
        m = mn;
    }
    __shared__ float2 gp[8];
    if (lane == 0) gp[grp] = make_float2(m, ssum);
    __syncthreads();
    if (tid == 0) {
        float M = gp[0].x, S = gp[0].y;
        for (int g = 1; g < 8; ++g) {
            float mg = gp[g].x, sg = gp[g].y;
            float mn = fmaxf(M, mg);
            S = S * __expf(M - mn) + sg * __expf(mg - mn);
            M = mn;
        }
        partials[b * SPLIT + split] = make_float2(M, S);
    }
}

// ---------------- momentum scatter-update (last-wins) ----------------
__global__ void kupdate(const int* __restrict__ indices, const float* __restrict__ bank,
                        const float* __restrict__ t_n, float* __restrict__ outBank /* d_out+1 */) {
    int j = blockIdx.x;
    int l = threadIdx.x;  // 64
    int idx = indices[j];
    for (int j2 = j + 1; j2 < B_SZ; ++j2)
        if (indices[j2] == idx) return;  // last occurrence wins
    float2 bv = ((const float2*)(bank + (long long)idx * D_SZ))[l];
    float2 tv = ((const float2*)(t_n + j * D_SZ))[l];
    float2 u = {MOM * bv.x + (1.0f - MOM) * tv.x, MOM * bv.y + (1.0f - MOM) * tv.y};
    float ss = u.x * u.x + u.y * u.y;
    for (int m = 1; m < 64; m <<= 1) ss += __shfl_xor(ss, m, 64);
    float inv = 1.0f / fmaxf(sqrtf(ss), EPSN);
    float* dst = outBank + (long long)idx * D_SZ + l * 2;
    dst[0] = u.x * inv;
    dst[1] = u.y * inv;
}

// ---------------- combine partials -> loss ----------------
__global__ void kfinal(const float2* __restrict__ partials, const float* __restrict__ pos,
                       float* __restrict__ out) {
    __shared__ float red[B_SZ];
    int t = threadIdx.x;  // 512
    float M = -INFINITY, S = 0.0f;
    for (int p = 0; p < SPLIT; ++p) {
        float2 ms = partials[t * SPLIT + p];
        float mn = fmaxf(M, ms.x);
        S = S * __expf(M - mn) + ms.y * __expf(ms.x - mn);
        M = mn;
    }
    float pl = pos[t];
    float mn = fmaxf(M, pl);
    S = S * __expf(M - mn) + __expf(pl - mn);
    M = mn;
    red[t] = M + logf(S) - pl;
    __syncthreads();
    for (int off = 256; off > 0; off >>= 1) {
        if (t < off) red[t] += red[t + off];
        __syncthreads();
    }
    if (t == 0) out[0] = red[0] * (1.0f / (float)B_SZ);
}

extern "C" void kernel_launch(void* const* d_in, const int* in_sizes, int n_in,
                              void* d_out, int out_size, void* d_ws, size_t ws_size,
                              hipStream_t stream) {
    const float* student = (const float*)d_in[0];
    const float* teacher = (const float*)d_in[1];
    const float* bank    = (const float*)d_in[2];
    const int*   indices = (const int*)d_in[3];
    const int*   negidx  = (const int*)d_in[4];
    float* out = (float*)d_out;

    // workspace: small arrays in first 1 MB, bf16 shadow bank after
    float* s_n      = (float*)d_ws;              // 65536 f
    float* t_n      = s_n + B_SZ * D_SZ;         // 65536 f
    float* pos      = t_n + B_SZ * D_SZ;         // 512 f
    float2* partials = (float2*)(pos + B_SZ);    // 512*SPLIT float2 (32 KB)
    u16x4* wsb = (u16x4*)((char*)d_ws + WSB_OFF);
    const size_t need = (size_t)WSB_OFF + (size_t)NDATA * D_SZ * 2;
    const bool use_bf16 = ws_size >= need;

    knorm<<<B_SZ, 64, 0, stream>>>(student, teacher, s_n, t_n, pos);
    dim3 g(SPLIT, B_SZ);
    if (use_bf16) {
        kcopy_emit<<<4096, 256, 0, stream>>>(bank, out, wsb);
        kneg_bf16<<<g, 256, 0, stream>>>(wsb, negidx, s_n, partials);
    } else {
        kcopy_plain<<<4096, 256, 0, stream>>>(bank, out);
        kneg_f32<<<g, 256, 0, stream>>>(bank, negidx, s_n, partials);
    }
    kupdate<<<B_SZ, 64, 0, stream>>>(indices, bank, t_n, out + 1);
    kfinal<<<1, B_SZ, 0, stream>>>(partials, pos, out);
}

// Round 9
// 175.662 us; speedup vs baseline: 3.2406x; 1.2451x over previous
//
#include <hip/hip_runtime.h>
#include <cmath>

#define B_SZ 512
#define D_SZ 128
#define K_SZ 4096
#define NDATA 500000
#define TEMP 0.07f
#define MOM 0.5f
#define EPSN 1e-12f
#define SPLIT 8
#define WSB_OFF (1 << 20)  // fp8 shadow bank offset in d_ws (bytes)

typedef float f32x4 __attribute__((ext_vector_type(4)));
typedef float f32x2 __attribute__((ext_vector_type(2)));

// ---------------- kernel A: normalize s,t + pos logits ----------------
__global__ void knorm(const float* __restrict__ s_in, const float* __restrict__ t_in,
                      float* __restrict__ s_n, float* __restrict__ t_n,
                      float* __restrict__ pos) {
    int b = blockIdx.x;
    int l = threadIdx.x;  // 64 lanes, 2 floats each
    float2 sv = ((const float2*)(s_in + b * D_SZ))[l];
    float2 tv = ((const float2*)(t_in + b * D_SZ))[l];
    float ss = sv.x * sv.x + sv.y * sv.y;
    float tt = tv.x * tv.x + tv.y * tv.y;
    for (int m = 1; m < 64; m <<= 1) {
        ss += __shfl_xor(ss, m, 64);
        tt += __shfl_xor(tt, m, 64);
    }
    float sinv = 1.0f / fmaxf(sqrtf(ss), EPSN);
    float tinv = 1.0f / fmaxf(sqrtf(tt), EPSN);
    float2 sn = {sv.x * sinv, sv.y * sinv};
    float2 tn = {tv.x * tinv, tv.y * tinv};
    ((float2*)(s_n + b * D_SZ))[l] = sn;
    ((float2*)(t_n + b * D_SZ))[l] = tn;
    float d = sn.x * tn.x + sn.y * tn.y;
    for (int m = 1; m < 64; m <<= 1) d += __shfl_xor(d, m, 64);
    if (l == 0) pos[b] = d * (1.0f / TEMP);
}

// ---------------- copy: bank -> out+1 (NT f32 streams) + fp8 shadow (cached) ----------------
__global__ __launch_bounds__(256) void kcopy_emit(const float* __restrict__ src,
                                                  float* __restrict__ out /* d_out */,
                                                  unsigned int* __restrict__ wsb) {
    const long long total = (long long)NDATA * D_SZ;  // 64,000,000
    const long long NV = total / 4;                   // 16,000,000
    long long t = blockIdx.x * 256LL + threadIdx.x;
    const long long nthr = gridDim.x * 256LL;
    const int lane = threadIdx.x & 63;
    const f32x4* src4 = (const f32x4*)src;
    f32x4* out4 = (f32x4*)out;
    for (long long j = t; j < NV; j += nthr) {
        f32x4 v = __builtin_nontemporal_load(src4 + j);
        // encode 4 floats -> 4 fp8 (e4m3, OCP on gfx950) in one dword
        int w8 = __builtin_amdgcn_cvt_pk_fp8_f32(v.x, v.y, 0, false);
        w8 = __builtin_amdgcn_cvt_pk_fp8_f32(v.z, v.w, w8, true);
        wsb[j] = (unsigned int)w8;  // regular store -> stays in L3 for the gather
        float pw = __shfl_up(v.w, 1, 64);
        if (lane == 0 && j > 0) pw = src[4 * j - 1];
        if (j > 0) {
            f32x4 w;
            w.x = pw; w.y = v.x; w.z = v.y; w.w = v.z;
            __builtin_nontemporal_store(w, out4 + j);
        } else {
            out[1] = v.x; out[2] = v.y; out[3] = v.z;
            out[total] = src[total - 1];
        }
    }
}

// ---------------- gather from fp8 shadow: 8 lanes/row, 16B/lane ----------------
__global__ __launch_bounds__(256) void kneg_fp8(const unsigned int* __restrict__ wsb,
                                                const int* __restrict__ negidx,
                                                const float* __restrict__ s_n,
                                                float2* __restrict__ partials) {
    const int split = blockIdx.x;   // 0..SPLIT-1
    const int b = blockIdx.y;
    const int tid = threadIdx.x;
    const int oct = tid >> 3;       // 32 octets of 8 lanes
    const int o = tid & 7;
    // preload this lane's 16-element s chunk into registers
    const f32x4* sn4 = (const f32x4*)(s_n + b * D_SZ + o * 16);
    f32x4 s0 = sn4[0], s1 = sn4[1], s2 = sn4[2], s3 = sn4[3];
    float m = -INFINITY, ssum = 0.0f;
    const int KB = K_SZ / SPLIT;             // 512 rows per block
    const int base = b * K_SZ + split * KB;
    for (int it = 0; it < KB / 128; ++it) {  // 4 iters; octet does 4 rows/iter
        int k = it * 128 + oct * 4;
        int4 idx = *(const int4*)(negidx + base + k);
        uint4 h0 = ((const uint4*)(wsb + (long long)idx.x * 32))[o];
        uint4 h1 = ((const uint4*)(wsb + (long long)idx.y * 32))[o];
        uint4 h2 = ((const uint4*)(wsb + (long long)idx.z * 32))[o];
        uint4 h3 = ((const uint4*)(wsb + (long long)idx.w * 32))[o];
        float d0 = 0.0f, d1 = 0.0f, d2 = 0.0f, d3 = 0.0f;
        {
            f32x2 a, c;
            a = __builtin_amdgcn_cvt_pk_f32_fp8((int)h0.x, false);
            c = __builtin_amdgcn_cvt_pk_f32_fp8((int)h0.x, true);
            d0 += a.x * s0.x + a.y * s0.y + c.x * s0.z + c.y * s0.w;
            a = __builtin_amdgcn_cvt_pk_f32_fp8((int)h0.y, false);
            c = __builtin_amdgcn_cvt_pk_f32_fp8((int)h0.y, true);
            d0 += a.x * s1.x + a.y * s1.y + c.x * s1.z + c.y * s1.w;
            a = __builtin_amdgcn_cvt_pk_f32_fp8((int)h0.z, false);
            c = __builtin_amdgcn_cvt_pk_f32_fp8((int)h0.z, true);
            d0 += a.x * s2.x + a.y * s2.y + c.x * s2.z + c.y * s2.w;
            a = __builtin_amdgcn_cvt_pk_f32_fp8((int)h0.w, false);
            c = __builtin_amdgcn_cvt_pk_f32_fp8((int)h0.w, true);
            d0 += a.x * s3.x + a.y * s3.y + c.x * s3.z + c.y * s3.w;

            a = __builtin_amdgcn_cvt_pk_f32_fp8((int)h1.x, false);
            c = __builtin_amdgcn_cvt_pk_f32_fp8((int)h1.x, true);
            d1 += a.x * s0.x + a.y * s0.y + c.x * s0.z + c.y * s0.w;
            a = __builtin_amdgcn_cvt_pk_f32_fp8((int)h1.y, false);
            c = __builtin_amdgcn_cvt_pk_f32_fp8((int)h1.y, true);
            d1 += a.x * s1.x + a.y * s1.y + c.x * s1.z + c.y * s1.w;
            a = __builtin_amdgcn_cvt_pk_f32_fp8((int)h1.z, false);
            c = __builtin_amdgcn_cvt_pk_f32_fp8((int)h1.z, true);
            d1 += a.x * s2.x + a.y * s2.y + c.x * s2.z + c.y * s2.w;
            a = __builtin_amdgcn_cvt_pk_f32_fp8((int)h1.w, false);
            c = __builtin_amdgcn_cvt_pk_f32_fp8((int)h1.w, true);
            d1 += a.x * s3.x + a.y * s3.y + c.x * s3.z + c.y * s3.w;

            a = __builtin_amdgcn_cvt_pk_f32_fp8((int)h2.x, false);
            c = __builtin_amdgcn_cvt_pk_f32_fp8((int)h2.x, true);
            d2 += a.x * s0.x + a.y * s0.y + c.x * s0.z + c.y * s0.w;
            a = __builtin_amdgcn_cvt_pk_f32_fp8((int)h2.y, false);
            c = __builtin_amdgcn_cvt_pk_f32_fp8((int)h2.y, true);
            d2 += a.x * s1.x + a.y * s1.y + c.x * s1.z + c.y * s1.w;
            a = __builtin_amdgcn_cvt_pk_f32_fp8((int)h2.z, false);
            c = __builtin_amdgcn_cvt_pk_f32_fp8((int)h2.z, true);
            d2 += a.x * s2.x + a.y * s2.y + c.x * s2.z + c.y * s2.w;
            a = __builtin_amdgcn_cvt_pk_f32_fp8((int)h2.w, false);
            c = __builtin_amdgcn_cvt_pk_f32_fp8((int)h2.w, true);
            d2 += a.x * s3.x + a.y * s3.y + c.x * s3.z + c.y * s3.w;

            a = __builtin_amdgcn_cvt_pk_f32_fp8((int)h3.x, false);
            c = __builtin_amdgcn_cvt_pk_f32_fp8((int)h3.x, true);
            d3 += a.x * s0.x + a.y * s0.y + c.x * s0.z + c.y * s0.w;
            a = __builtin_amdgcn_cvt_pk_f32_fp8((int)h3.y, false);
            c = __builtin_amdgcn_cvt_pk_f32_fp8((int)h3.y, true);
            d3 += a.x * s1.x + a.y * s1.y + c.x * s1.z + c.y * s1.w;
            a = __builtin_amdgcn_cvt_pk_f32_fp8((int)h3.z, false);
            c = __builtin_amdgcn_cvt_pk_f32_fp8((int)h3.z, true);
            d3 += a.x * s2.x + a.y * s2.y + c.x * s2.z + c.y * s2.w;
            a = __builtin_amdgcn_cvt_pk_f32_fp8((int)h3.w, false);
            c = __builtin_amdgcn_cvt_pk_f32_fp8((int)h3.w, true);
            d3 += a.x * s3.x + a.y * s3.y + c.x * s3.z + c.y * s3.w;
        }
        // reduce across the 8-lane octet
        for (int s = 1; s < 8; s <<= 1) {
            d0 += __shfl_xor(d0, s, 64);
            d1 += __shfl_xor(d1, s, 64);
            d2 += __shfl_xor(d2, s, 64);
            d3 += __shfl_xor(d3, s, 64);
        }
        d0 *= (1.0f / TEMP);
        d1 *= (1.0f / TEMP);
        d2 *= (1.0f / TEMP);
        d3 *= (1.0f / TEMP);
        float mx = fmaxf(fmaxf(d0, d1), fmaxf(d2, d3));
        float mn = fmaxf(m, mx);
        ssum = ssum * __expf(m - mn) + __expf(d0 - mn) + __expf(d1 - mn) +
               __expf(d2 - mn) + __expf(d3 - mn);
        m = mn;
    }
    __shared__ float2 gp[32];
    if (o == 0) gp[oct] = make_float2(m, ssum);
    __syncthreads();
    if (tid == 0) {
        float M = gp[0].x, S = gp[0].y;
        for (int g = 1; g < 32; ++g) {
            float mg = gp[g].x, sg = gp[g].y;
            float mn = fmaxf(M, mg);
            S = S * __expf(M - mn) + sg * __expf(mg - mn);
            M = mn;
        }
        partials[b * SPLIT + split] = make_float2(M, S);
    }
}

// ---------------- momentum scatter-update (last-wins) ----------------
__global__ void kupdate(const int* __restrict__ indices, const float* __restrict__ bank,
                        const float* __restrict__ t_n, float* __restrict__ outBank /* d_out+1 */) {
    int j = blockIdx.x;
    int l = threadIdx.x;  // 64
    int idx = indices[j];
    for (int j2 = j + 1; j2 < B_SZ; ++j2)
        if (indices[j2] == idx) return;  // last occurrence wins
    float2 bv = ((const float2*)(bank + (long long)idx * D_SZ))[l];
    float2 tv = ((const float2*)(t_n + j * D_SZ))[l];
    float2 u = {MOM * bv.x + (1.0f - MOM) * tv.x, MOM * bv.y + (1.0f - MOM) * tv.y};
    float ss = u.x * u.x + u.y * u.y;
    for (int m = 1; m < 64; m <<= 1) ss += __shfl_xor(ss, m, 64);
    float inv = 1.0f / fmaxf(sqrtf(ss), EPSN);
    float* dst = outBank + (long long)idx * D_SZ + l * 2;
    dst[0] = u.x * inv;
    dst[1] = u.y * inv;
}

// ---------------- combine partials -> loss ----------------
__global__ void kfinal(const float2* __restrict__ partials, const float* __restrict__ pos,
                       float* __restrict__ out) {
    __shared__ float red[B_SZ];
    int t = threadIdx.x;  // 512
    float M = -INFINITY, S = 0.0f;
    for (int p = 0; p < SPLIT; ++p) {
        float2 ms = partials[t * SPLIT + p];
        float mn = fmaxf(M, ms.x);
        S = S * __expf(M - mn) + ms.y * __expf(ms.x - mn);
        M = mn;
    }
    float pl = pos[t];
    float mn = fmaxf(M, pl);
    S = S * __expf(M - mn) + __expf(pl - mn);
    M = mn;
    red[t] = M + logf(S) - pl;
    __syncthreads();
    for (int off = 256; off > 0; off >>= 1) {
        if (t < off) red[t] += red[t + off];
        __syncthreads();
    }
    if (t == 0) out[0] = red[0] * (1.0f / (float)B_SZ);
}

extern "C" void kernel_launch(void* const* d_in, const int* in_sizes, int n_in,
                              void* d_out, int out_size, void* d_ws, size_t ws_size,
                              hipStream_t stream) {
    const float* student = (const float*)d_in[0];
    const float* teacher = (const float*)d_in[1];
    const float* bank    = (const float*)d_in[2];
    const int*   indices = (const int*)d_in[3];
    const int*   negidx  = (const int*)d_in[4];
    float* out = (float*)d_out;

    // workspace: small arrays in first 1 MB, fp8 shadow bank after (61 MB)
    float* s_n      = (float*)d_ws;              // 65536 f
    float* t_n      = s_n + B_SZ * D_SZ;         // 65536 f
    float* pos      = t_n + B_SZ * D_SZ;         // 512 f
    float2* partials = (float2*)(pos + B_SZ);    // 512*SPLIT float2
    unsigned int* wsb = (unsigned int*)((char*)d_ws + WSB_OFF);

    knorm<<<B_SZ, 64, 0, stream>>>(student, teacher, s_n, t_n, pos);
    kcopy_emit<<<4096, 256, 0, stream>>>(bank, out, wsb);
    dim3 g(SPLIT, B_SZ);
    kneg_fp8<<<g, 256, 0, stream>>>(wsb, negidx, s_n, partials);
    kupdate<<<B_SZ, 64, 0, stream>>>(indices, bank, t_n, out + 1);
    kfinal<<<1, B_SZ, 0, stream>>>(partials, pos, out);
}